// Round 6
// baseline (362.422 us; speedup 1.0000x reference)
//
#include <hip/hip_runtime.h>

// ---------------------------------------------------------------------------
// Attention: out = softmax(BETA * (X_q Wq + bq)(X_k Wk + bk)^T) (X_v Wv + bv)
// B=4, S=2048, D=1024, KEY_DIM=VALUE_DIM=1024, BETA=1/32.
// R12: eliminate the cast3 pass (144 MB traffic, ~30us). Projections read
//  fp32 X directly: A staged to LDS as fp32 via global_load_lds (32KB) +
//  B bf16 (16KB) = 48KB single buffer -> 3 blocks/CU; A fragments converted
//  to bf16 AFTER the LDS read with native casts (v_cvt_pk_bf16_f32, RNE =
//  bit-identical to the old cast3+bf16 path). A swizzle is 32B-granular
//  (c ^= (r&7)<<1, bit0 kept so b128 pairs stay adjacent; <=2-way conflicts).
//  K-tile split into 2 ks-sub-phases to cap live VGPRs (~3 waves/SIMD).
//  score/pv GEMMs and softmax unchanged from R11 (604 TF plateau; 5 schedule
//  variants all ~25% MfmaUtil -> stop tuning schedule, cut memory passes).
// ---------------------------------------------------------------------------

typedef __bf16 bf16x8 __attribute__((ext_vector_type(8)));
typedef float f32x4 __attribute__((ext_vector_type(4)));

#define MIB ((size_t)1 << 20)

__device__ __forceinline__ unsigned short f2b(float f) {
  unsigned int u = __float_as_uint(f);
  return (unsigned short)((u + 0x7FFFu + ((u >> 16) & 1u)) >> 16);
}

__device__ __forceinline__ void async16(const void* g, void* l) {
  __builtin_amdgcn_global_load_lds(
      (const __attribute__((address_space(1))) unsigned int*)g,
      (__attribute__((address_space(3))) unsigned int*)l, 16, 0, 0);
}

__device__ __forceinline__ unsigned ldsoff(const void* p) {
  return (unsigned)(size_t)(const __attribute__((address_space(3))) char*)p;
}

// Raw b128 LDS reads, invisible to the compiler's waitcnt insertion.
__device__ __forceinline__ bf16x8 ds_read16(unsigned off) {
  bf16x8 r;
  asm volatile("ds_read_b128 %0, %1" : "=v"(r) : "v"(off));
  return r;
}
__device__ __forceinline__ f32x4 ds_read16f(unsigned off) {
  f32x4 r;
  asm volatile("ds_read_b128 %0, %1" : "=v"(r) : "v"(off));
  return r;
}

__device__ __forceinline__ bf16x8 cvt8(f32x4 lo, f32x4 hi) {
  bf16x8 r;
  r[0] = (__bf16)lo[0]; r[1] = (__bf16)lo[1];
  r[2] = (__bf16)lo[2]; r[3] = (__bf16)lo[3];
  r[4] = (__bf16)hi[0]; r[5] = (__bf16)hi[1];
  r[6] = (__bf16)hi[2]; r[7] = (__bf16)hi[3];
  return r;
}

// ---------------------------------------------------------------------------
// Projection staging: A fp32 128x64 (32KB, 16B-chunk swizzle c^((r&7)<<1)) +
// B bf16 128x64 (16KB, chunk swizzle c^(r&7)). Linear LDS dest + permuted
// global source (both-sides rule). 12 async16 per thread.
// ---------------------------------------------------------------------------
__device__ __forceinline__ void stage_tile_f32(
    const float* __restrict__ A, const unsigned short* __restrict__ Bt,
    char* dst, int K, int kb, int tid) {
#pragma unroll
  for (int i = 0; i < 8; ++i) {
    const int e = i * 256 + tid;  // A chunk slot (16B = 4 floats)
    const int r = e >> 4;
    const int cg = (e & 15) ^ ((r & 7) << 1);
    async16(A + (size_t)r * K + kb + cg * 4, dst + e * 16);
  }
#pragma unroll
  for (int i = 0; i < 4; ++i) {
    const int e = i * 256 + tid;  // B chunk slot (16B = 8 bf16)
    const int r = e >> 3;
    const int cg = (e & 7) ^ (r & 7);
    async16(Bt + (size_t)r * K + kb + cg * 8, dst + 32768 + e * 16);
  }
}

// ---------------------------------------------------------------------------
// Projection GEMM K-loop (fp32 A in LDS, bf16 B), single 48KB buffer,
// 2 ks-sub-phases per K-tile. 4 waves 2x2; wave tile 64x64.
// SWAP=true -> transposed C fragment (lane owns 4 consecutive n).
// ---------------------------------------------------------------------------
template <bool SWAP>
__device__ __forceinline__ void gemm_loop_proj(
    const float* __restrict__ A, const unsigned short* __restrict__ Bt,
    char* lds, int K, int m0, int n0, f32x4 (&acc)[4][4]) {
  const int tid = threadIdx.x;
  const int lane = tid & 63;
  const int wave = tid >> 6;
  const int wm = (wave >> 1) * 64;
  const int wn = (wave & 1) * 64;
  const int fr = lane & 15;
  const int q = lane >> 4;
  const int NT = K >> 6;

  const float* Ab = A + (size_t)m0 * K;
  const unsigned short* Bb = Bt + (size_t)n0 * K;
  const unsigned LB = ldsoff(lds);

  // Loop-invariant byte offsets. A: row 256B, slot pair (2*kc)^((R&7)<<1).
  unsigned oa[2][4], ob[2][4];
#pragma unroll
  for (int mi = 0; mi < 4; ++mi) {
    const int R = wm + mi * 16 + fr;
#pragma unroll
    for (int ks = 0; ks < 2; ++ks) {
      const int kc = ks * 4 + q;
      oa[ks][mi] = (unsigned)(R * 256 + (((2 * kc) ^ ((R & 7) << 1)) << 4));
    }
  }
#pragma unroll
  for (int ni = 0; ni < 4; ++ni) {
    const int R = wn + ni * 16 + fr;
#pragma unroll
    for (int ks = 0; ks < 2; ++ks) {
      const int kc = ks * 4 + q;
      ob[ks][ni] = (unsigned)(32768 + R * 128 + ((kc ^ (R & 7)) << 4));
    }
  }

  for (int t = 0; t < NT; ++t) {
    stage_tile_f32(Ab, Bb, lds, K, t << 6, tid);
    __syncthreads();  // vmcnt(0)+barrier: tile resident

#pragma unroll
    for (int ks = 0; ks < 2; ++ks) {
      f32x4 alo[4], ahi[4];
      bf16x8 bv[4];
#pragma unroll
      for (int mi = 0; mi < 4; ++mi) {
        alo[mi] = ds_read16f(LB + oa[ks][mi]);
        ahi[mi] = ds_read16f(LB + oa[ks][mi] + 16);
      }
#pragma unroll
      for (int ni = 0; ni < 4; ++ni) bv[ni] = ds_read16(LB + ob[ks][ni]);

      asm volatile("s_waitcnt lgkmcnt(0)");
      __builtin_amdgcn_sched_barrier(0);

      bf16x8 av[4];
#pragma unroll
      for (int mi = 0; mi < 4; ++mi) av[mi] = cvt8(alo[mi], ahi[mi]);

#pragma unroll
      for (int mi = 0; mi < 4; ++mi)
#pragma unroll
        for (int ni = 0; ni < 4; ++ni)
          acc[mi][ni] = SWAP ? __builtin_amdgcn_mfma_f32_16x16x32_bf16(
                                   bv[ni], av[mi], acc[mi][ni], 0, 0, 0)
                             : __builtin_amdgcn_mfma_f32_16x16x32_bf16(
                                   av[mi], bv[ni], acc[mi][ni], 0, 0, 0);
    }
    __syncthreads();  // all reads done before restage
  }
}

// ---------------------------------------------------------------------------
// bf16-input GEMM K-loop (scores / PV), double-buffered, from R11.
// ---------------------------------------------------------------------------
template <int TN>
__device__ __forceinline__ void stage_tile(
    const unsigned short* __restrict__ A, const unsigned short* __restrict__ Bt,
    unsigned short* dst, int K, int kb, int tid) {
#pragma unroll
  for (int i = 0; i < 4; ++i) {
    const int e = i * 256 + tid;
    const int r = e >> 3;
    const int cg = (e & 7) ^ (r & 7);
    async16(A + (size_t)r * K + kb + cg * 8, dst + e * 8);
  }
#pragma unroll
  for (int i = 0; i < TN / 32; ++i) {
    const int e = i * 256 + tid;
    const int r = e >> 3;
    const int cg = (e & 7) ^ (r & 7);
    async16(Bt + (size_t)r * K + kb + cg * 8, dst + 128 * 64 + e * 8);
  }
}

template <int TN, bool SWAP>
__device__ __forceinline__ void gemm_loop(
    const unsigned short* __restrict__ A, const unsigned short* __restrict__ Bt,
    unsigned short* lds, int K, int m0, int n0, f32x4 (&acc)[4][TN / 32]) {
  constexpr int NI = TN / 32;
  constexpr unsigned BUFB = (128 + TN) * 64 * 2;  // bytes per buffer
  const int tid = threadIdx.x;
  const int lane = tid & 63;
  const int wave = tid >> 6;
  const int wm = (wave >> 1) * 64;
  const int wn = (wave & 1) * (TN / 2);
  const int fr = lane & 15;
  const int q = lane >> 4;
  const int NT = K >> 6;

  const unsigned short* Ab = A + (size_t)m0 * K;
  const unsigned short* Bb = Bt + (size_t)n0 * K;
  const unsigned LB = ldsoff(lds);

  unsigned oa[4][2], ob[NI][2];
#pragma unroll
  for (int mi = 0; mi < 4; ++mi) {
    const int R = wm + mi * 16 + fr;
#pragma unroll
    for (int ks = 0; ks < 2; ++ks) {
      const int kc = ks * 4 + q;
      oa[mi][ks] = (unsigned)((R * 64 + ((kc ^ (R & 7)) << 3)) * 2);
    }
  }
#pragma unroll
  for (int ni = 0; ni < NI; ++ni) {
    const int R = wn + ni * 16 + fr;
#pragma unroll
    for (int ks = 0; ks < 2; ++ks) {
      const int kc = ks * 4 + q;
      ob[ni][ks] =
          (unsigned)(128 * 64 * 2 + (R * 64 + ((kc ^ (R & 7)) << 3)) * 2);
    }
  }

  stage_tile<TN>(Ab, Bb, lds, K, 0, tid);
  __syncthreads();

  for (int t = 0; t < NT; ++t) {
    const unsigned boff = LB + (unsigned)(t & 1) * BUFB;
    if (t + 1 < NT)
      stage_tile<TN>(Ab, Bb, lds + ((t + 1) & 1) * (BUFB / 2), K,
                     (t + 1) << 6, tid);

    bf16x8 av[2][4], bv[2][NI];
#pragma unroll
    for (int ks = 0; ks < 2; ++ks)
#pragma unroll
      for (int mi = 0; mi < 4; ++mi) av[ks][mi] = ds_read16(boff + oa[mi][ks]);
#pragma unroll
    for (int ks = 0; ks < 2; ++ks)
#pragma unroll
      for (int ni = 0; ni < NI; ++ni) bv[ks][ni] = ds_read16(boff + ob[ni][ks]);

    asm volatile("s_waitcnt lgkmcnt(0)");
    __builtin_amdgcn_sched_barrier(0);

#pragma unroll
    for (int ks = 0; ks < 2; ++ks)
#pragma unroll
      for (int mi = 0; mi < 4; ++mi)
#pragma unroll
        for (int ni = 0; ni < NI; ++ni)
          acc[mi][ni] = SWAP ? __builtin_amdgcn_mfma_f32_16x16x32_bf16(
                                   bv[ks][ni], av[ks][mi], acc[mi][ni], 0, 0, 0)
                             : __builtin_amdgcn_mfma_f32_16x16x32_bf16(
                                   av[ks][mi], bv[ks][ni], acc[mi][ni], 0, 0, 0);

    __syncthreads();
  }
}

// ---------------------------------------------------------------------------
// q/k projection (SWAP layout, fp32 A input), grid (8, 64, 2): z = {q,k}.
// ---------------------------------------------------------------------------
struct ProjArgs {
  const float* A[3];
  const unsigned short* Bt[3];
  unsigned short* C[3];
  const float* bias[3];
};

__global__ __launch_bounds__(256) void proj_qk(ProjArgs p) {
  __shared__ __align__(16) char lds[49152];
  const int z = blockIdx.z;
  const int m0 = blockIdx.y * 128;
  const int n0 = blockIdx.x * 128;

  f32x4 acc[4][4] = {};
  gemm_loop_proj<true>(p.A[z], p.Bt[z], lds, 1024, m0, n0, acc);

  const int lane = threadIdx.x & 63;
  const int wave = threadIdx.x >> 6;
  const int wm = (wave >> 1) * 64;
  const int wn = (wave & 1) * 64;
  const int fr = lane & 15;
  const int q4 = (lane >> 4) * 4;
  const float* bias = p.bias[z];
  unsigned short* C = p.C[z];

  // SWAP layout: row m = fr (+16*mi), cols n = q4 + r (+16*ni).
#pragma unroll
  for (int mi = 0; mi < 4; ++mi) {
    const int m = m0 + wm + mi * 16 + fr;
#pragma unroll
    for (int ni = 0; ni < 4; ++ni) {
      const int nb = n0 + wn + ni * 16 + q4;
      const float4 bb = *(const float4*)&bias[nb];
      ushort4 o = make_ushort4(
          f2b(acc[mi][ni][0] + bb.x), f2b(acc[mi][ni][1] + bb.y),
          f2b(acc[mi][ni][2] + bb.z), f2b(acc[mi][ni][3] + bb.w));
      *(ushort4*)&C[(size_t)m * 1024 + nb] = o;
    }
  }
}

// ---------------------------------------------------------------------------
// v projection (unswapped, fp32 A input), grid (8, 64, 1): writes vT[b][n][s].
// ---------------------------------------------------------------------------
__global__ __launch_bounds__(256) void proj_v(ProjArgs p) {
  __shared__ __align__(16) char lds[49152];
  const int m0 = blockIdx.y * 128;
  const int n0 = blockIdx.x * 128;

  f32x4 acc[4][4] = {};
  gemm_loop_proj<false>(p.A[2], p.Bt[2], lds, 1024, m0, n0, acc);

  const int lane = threadIdx.x & 63;
  const int wave = threadIdx.x >> 6;
  const int wm = (wave >> 1) * 64;
  const int wn = (wave & 1) * 64;
  const int fr = lane & 15;
  const int q4 = (lane >> 4) * 4;
  const float* bias = p.bias[2];

  // vT: per-batch [1024, 2048]; col n = fr (+16*ni), rows m = q4+r (+16*mi).
  unsigned short* C = p.C[2] + (size_t)(m0 >> 11) * (2048 * 1024);
#pragma unroll
  for (int mi = 0; mi < 4; ++mi) {
#pragma unroll
    for (int ni = 0; ni < 4; ++ni) {
      const int col = n0 + wn + ni * 16 + fr;
      const float bb = bias[col];
      const int rowb = (m0 + wm + mi * 16 + q4) & 2047;
      ushort4 o =
          make_ushort4(f2b(acc[mi][ni][0] + bb), f2b(acc[mi][ni][1] + bb),
                       f2b(acc[mi][ni][2] + bb), f2b(acc[mi][ni][3] + bb));
      *(ushort4*)&C[(size_t)col * 2048 + rowb] = o;
    }
  }
}

// ---------------------------------------------------------------------------
// Batched GEMM, fp32 out (SWAP layout -> float4 stores).
// ---------------------------------------------------------------------------
__global__ __launch_bounds__(256) void gemm_f32(
    const unsigned short* __restrict__ A, const unsigned short* __restrict__ Bt,
    float* __restrict__ C, int K, int ldc, long long sA, long long sB,
    long long sC) {
  __shared__ __align__(16) unsigned short lds[2 * 256 * 64];
  const int bz = blockIdx.z;
  A += (long long)bz * sA;
  Bt += (long long)bz * sB;
  C += (long long)bz * sC;
  const int m0 = blockIdx.y * 128;
  const int n0 = blockIdx.x * 128;

  f32x4 acc[4][4] = {};
  gemm_loop<128, true>(A, Bt, lds, K, m0, n0, acc);

  const int lane = threadIdx.x & 63;
  const int wave = threadIdx.x >> 6;
  const int wm = (wave >> 1) * 64;
  const int wn = (wave & 1) * 64;
  const int fr = lane & 15;
  const int q4 = (lane >> 4) * 4;
#pragma unroll
  for (int mi = 0; mi < 4; ++mi) {
    const int m = m0 + wm + mi * 16 + fr;
#pragma unroll
    for (int ni = 0; ni < 4; ++ni) {
      const int nb = n0 + wn + ni * 16 + q4;
      *(f32x4*)&C[(size_t)m * ldc + nb] = acc[mi][ni];
    }
  }
}

// ---------------------------------------------------------------------------
// Merged cast + transpose W [K,N] fp32 -> WT [N,K] bf16; z selects weight.
// ---------------------------------------------------------------------------
__global__ __launch_bounds__(256) void transpose3(
    const float* __restrict__ w0, const float* __restrict__ w1,
    const float* __restrict__ w2, unsigned short* __restrict__ t0,
    unsigned short* __restrict__ t1, unsigned short* __restrict__ t2) {
  __shared__ float t[32][33];
  const int K = 1024, N = 1024;
  const float* W = (blockIdx.z == 0) ? w0 : (blockIdx.z == 1) ? w1 : w2;
  unsigned short* WT = (blockIdx.z == 0) ? t0 : (blockIdx.z == 1) ? t1 : t2;
  const int n0 = blockIdx.x * 32, k0 = blockIdx.y * 32;
  const int tx = threadIdx.x, ty = threadIdx.y;  // block (32,8)
#pragma unroll
  for (int i = 0; i < 32; i += 8)
    t[ty + i][tx] = W[(size_t)(k0 + ty + i) * N + (n0 + tx)];
  __syncthreads();
#pragma unroll
  for (int i = 0; i < 32; i += 8)
    WT[(size_t)(n0 + ty + i) * K + (k0 + tx)] = f2b(t[tx][ty + i]);
}

// ---------------------------------------------------------------------------
// Row softmax: P[row,:] = softmax(BETA * S[row,:]) as bf16. One block/row.
// ---------------------------------------------------------------------------
__global__ __launch_bounds__(256) void softmax_rows(const float* __restrict__ S,
                                                    unsigned short* __restrict__ P) {
  const int cols = 2048;
  const size_t row = blockIdx.x;
  const float4* srow = (const float4*)(S + row * cols);
  const int tid = threadIdx.x;
  const int lane = tid & 63;
  const int wave = tid >> 6;

  float4 a = srow[tid];
  float4 b = srow[tid + 256];

  float mx = fmaxf(fmaxf(fmaxf(a.x, a.y), fmaxf(a.z, a.w)),
                   fmaxf(fmaxf(b.x, b.y), fmaxf(b.z, b.w)));
#pragma unroll
  for (int o = 1; o < 64; o <<= 1) mx = fmaxf(mx, __shfl_xor(mx, o));

  __shared__ float red[8];
  if (lane == 0) red[wave] = mx;
  __syncthreads();
  mx = fmaxf(fmaxf(red[0], red[1]), fmaxf(red[2], red[3]));

  const float c = 0.03125f * 1.4426950408889634f;  // BETA * log2(e)
  float4 pa, pb;
  pa.x = exp2f((a.x - mx) * c); pa.y = exp2f((a.y - mx) * c);
  pa.z = exp2f((a.z - mx) * c); pa.w = exp2f((a.w - mx) * c);
  pb.x = exp2f((b.x - mx) * c); pb.y = exp2f((b.y - mx) * c);
  pb.z = exp2f((b.z - mx) * c); pb.w = exp2f((b.w - mx) * c);

  float sum = pa.x + pa.y + pa.z + pa.w + pb.x + pb.y + pb.z + pb.w;
#pragma unroll
  for (int o = 1; o < 64; o <<= 1) sum += __shfl_xor(sum, o);
  if (lane == 0) red[4 + wave] = sum;
  __syncthreads();
  sum = red[4] + red[5] + red[6] + red[7];

  const float inv = 1.0f / sum;
  ushort4* prow = (ushort4*)(P + row * cols);
  prow[tid] = make_ushort4(f2b(pa.x * inv), f2b(pa.y * inv), f2b(pa.z * inv),
                           f2b(pa.w * inv));
  prow[tid + 256] = make_ushort4(f2b(pb.x * inv), f2b(pb.y * inv),
                                 f2b(pb.z * inv), f2b(pb.w * inv));
}

// ---------------------------------------------------------------------------
extern "C" void kernel_launch(void* const* d_in, const int* in_sizes, int n_in,
                              void* d_out, int out_size, void* d_ws, size_t ws_size,
                              hipStream_t stream) {
  const float* query = (const float*)d_in[0];
  const float* key_ = (const float*)d_in[1];
  const float* value = (const float*)d_in[2];
  const float* Wq = (const float*)d_in[3];
  const float* bq = (const float*)d_in[4];
  const float* Wk = (const float*)d_in[5];
  const float* bk = (const float*)d_in[6];
  const float* Wv = (const float*)d_in[7];
  const float* bv = (const float*)d_in[8];
  float* out = (float*)d_out;

  char* ws = (char*)d_ws;
  // Workspace layout (peak 166 MiB):
  //   [0,6)      WqT/WkT/WvT bf16 [1024,1024]
  //   [6,54)     P bf16 [8192,2048] (former cast region; cast pass removed)
  //   [54,102)   q bf16 [8192,1024], k bf16 [8192,1024], vT bf16 [4][1024,2048]
  //   [102,166)  scores fp32 [4,2048,2048]
  unsigned short* WqT = (unsigned short*)ws;
  unsigned short* WkT = WqT + (size_t)1024 * 1024;
  unsigned short* WvT = WkT + (size_t)1024 * 1024;
  unsigned short* qb = (unsigned short*)(ws + 54 * MIB);
  unsigned short* kb = (unsigned short*)(ws + 70 * MIB);
  unsigned short* vT = (unsigned short*)(ws + 86 * MIB);
  float* sc = (float*)(ws + 102 * MIB);
  unsigned short* P = (unsigned short*)(ws + 6 * MIB);

  transpose3<<<dim3(32, 32, 3), dim3(32, 8), 0, stream>>>(Wq, Wk, Wv, WqT, WkT,
                                                          WvT);

  ProjArgs pa;
  pa.A[0] = query;  pa.A[1] = key_;  pa.A[2] = value;
  pa.Bt[0] = WqT; pa.Bt[1] = WkT; pa.Bt[2] = WvT;
  pa.C[0] = qb;  pa.C[1] = kb;  pa.C[2] = vT;
  pa.bias[0] = bq; pa.bias[1] = bk; pa.bias[2] = bv;

  // q,k projections: swapped layout, ushort4 stores. 1024 blocks.
  proj_qk<<<dim3(8, 64, 2), 256, 0, stream>>>(pa);
  // v projection: unswapped, transposed vT out. 512 blocks.
  proj_v<<<dim3(8, 64, 1), 256, 0, stream>>>(pa);

  // scores[b] = q[b] @ k[b]^T : M=N=2048, K=1024, fp32 out. 1024 blocks.
  gemm_f32<<<dim3(16, 16, 4), 256, 0, stream>>>(
      qb, kb, sc, 1024, 2048, 2048LL * 1024, 2048LL * 1024, 2048LL * 2048);

  // P = softmax(BETA * scores), bf16
  softmax_rows<<<8192, 256, 0, stream>>>(sc, P);

  // out[b] = P[b] @ v[b] : M=2048, N=1024, K=2048. 512 blocks.
  gemm_f32<<<dim3(8, 16, 4), 256, 0, stream>>>(
      P, vT, out, 2048, 1024, 2048LL * 2048, 1024LL * 2048, 2048LL * 1024);
}